// Round 5
// baseline (746.015 us; speedup 1.0000x reference)
//
#include <hip/hip_runtime.h>
#include <hip/hip_bf16.h>

#define N_NODES 100000
#define N_EDGES 1600000
#define NF 64
#define EF 32

#define SCAN_B 512
#define SCAN_NB ((N_NODES + SCAN_B - 1) / SCAN_B)  // 196

// packed edge record (8B): [63:43]=e (21b) [42:26]=src (17b)
// [25:0]=float_bits(base)>>6 where base = s1[src]+s2[dst]+c
// (sign+exp8+mant17 -> abs err ~1e-4 on a |base|<~30 value).
// pad record: e=0, src=0, base=-inf  => exp(leaky(-inf+t)) = 0, no contrib.

__device__ __forceinline__ unsigned f2bf_rn(float x) {
  unsigned u = __float_as_uint(x);
  return (u + 0x7FFFu + ((u >> 16) & 1u)) >> 16;
}

// ---------------- K0: tiny prep — v = W_w^T a (160), c = W_b . a, and
// transposed copies of W_msg sub-blocks.
__global__ __launch_bounds__(256) void k0_prep(
    const float* __restrict__ Ww, const float* __restrict__ Wb,
    const float* __restrict__ a, const float* __restrict__ Wmsg,
    float* __restrict__ v, float* __restrict__ W1T, float* __restrict__ W2T,
    float* __restrict__ WmeT) {
  int t = threadIdx.x;
  for (int j = t; j < 160; j += 256) {
    float s = 0.f;
    for (int k = 0; k < 128; ++k) s = fmaf(a[k], Ww[k * 160 + j], s);
    v[j] = s;
  }
  if (t == 0) {
    float s = 0.f;
    for (int k = 0; k < 128; ++k) s = fmaf(a[k], Wb[k], s);
    v[160] = s;  // c
  }
  for (int idx = t; idx < 64 * 64; idx += 256) {
    int j = idx >> 6, i = idx & 63;
    W1T[idx] = Wmsg[i * 160 + j];        // src block, transposed [j][i]
    W2T[idx] = Wmsg[i * 160 + 64 + j];   // dst block
  }
  for (int idx = t; idx < 32 * 64; idx += 256) {
    int j = idx >> 6, i = idx & 63;
    WmeT[idx] = Wmsg[i * 160 + 128 + j]; // edge block
  }
}

// ---------------- K1: per-node precompute — s1, s2 scalars and
// m_src = W1 @ nf, m_dst = W2 @ nf, stored bf16 (packed 2/uint).
__global__ __launch_bounds__(256) void k1_node(
    const float* __restrict__ nf_g, const float* __restrict__ v,
    const float* __restrict__ W1T, const float* __restrict__ W2T,
    float* __restrict__ s1, float* __restrict__ s2,
    unsigned* __restrict__ m_srcH, unsigned* __restrict__ m_dstH) {
  int n = blockIdx.x * 256 + threadIdx.x;
  if (n >= N_NODES) return;
  const float4* nf4 = (const float4*)(nf_g + (size_t)n * NF);
  float acc[64];
#pragma unroll
  for (int i = 0; i < 64; ++i) acc[i] = 0.f;
  float s1a = 0.f, s2a = 0.f;
  for (int j4 = 0; j4 < 16; ++j4) {
    float4 q = nf4[j4];
    float xs[4] = {q.x, q.y, q.z, q.w};
#pragma unroll
    for (int u = 0; u < 4; ++u) {
      int j = j4 * 4 + u;
      float x = xs[u];
      s1a = fmaf(v[j], x, s1a);
      s2a = fmaf(v[64 + j], x, s2a);
      const float* w = W1T + j * 64;
#pragma unroll
      for (int i = 0; i < 64; ++i) acc[i] = fmaf(w[i], x, acc[i]);
    }
  }
  s1[n] = s1a;
  s2[n] = s2a;
  unsigned* ms = m_srcH + (size_t)n * 32;
#pragma unroll
  for (int i = 0; i < 32; ++i)
    ms[i] = f2bf_rn(acc[2 * i]) | (f2bf_rn(acc[2 * i + 1]) << 16);
#pragma unroll
  for (int i = 0; i < 64; ++i) acc[i] = 0.f;
  for (int j4 = 0; j4 < 16; ++j4) {
    float4 q = nf4[j4];
    float xs[4] = {q.x, q.y, q.z, q.w};
#pragma unroll
    for (int u = 0; u < 4; ++u) {
      int j = j4 * 4 + u;
      float x = xs[u];
      const float* w = W2T + j * 64;
#pragma unroll
      for (int i = 0; i < 64; ++i) acc[i] = fmaf(w[i], x, acc[i]);
    }
  }
  unsigned* md = m_dstH + (size_t)n * 32;
#pragma unroll
  for (int i = 0; i < 32; ++i)
    md[i] = f2bf_rn(acc[2 * i]) | (f2bf_rn(acc[2 * i + 1]) << 16);
}

// ---------------- degree count (int4 dst loads)
__global__ __launch_bounds__(256) void k_count(const int4* __restrict__ dst4,
                                               int* __restrict__ cnt) {
  int i = blockIdx.x * 256 + threadIdx.x;
  if (i < N_EDGES / 4) {
    int4 d = dst4[i];
    atomicAdd(&cnt[d.x], 1);
    atomicAdd(&cnt[d.y], 1);
    atomicAdd(&cnt[d.z], 1);
    atomicAdd(&cnt[d.w], 1);
  }
}

// ---------------- hierarchical scan
__global__ __launch_bounds__(SCAN_B) void kS1(const int* __restrict__ cnt,
                                              int* __restrict__ bsum) {
  __shared__ int sh[SCAN_B];
  int t = threadIdx.x;
  int i = blockIdx.x * SCAN_B + t;
  sh[t] = (i < N_NODES) ? cnt[i] : 0;
  __syncthreads();
  for (int d = SCAN_B / 2; d > 0; d >>= 1) {
    if (t < d) sh[t] += sh[t + d];
    __syncthreads();
  }
  if (t == 0) bsum[blockIdx.x] = sh[0];
}

__global__ __launch_bounds__(256) void kS2(const int* __restrict__ bsum,
                                           int* __restrict__ boff,
                                           int* __restrict__ row_ptr) {
  __shared__ int sh[256];
  int t = threadIdx.x;
  sh[t] = (t < SCAN_NB) ? bsum[t] : 0;
  __syncthreads();
  for (int d = 1; d < 256; d <<= 1) {
    int val = (t >= d) ? sh[t - d] : 0;
    __syncthreads();
    sh[t] += val;
    __syncthreads();
  }
  if (t < SCAN_NB) boff[t] = (t == 0) ? 0 : sh[t - 1];
  if (t == 255) row_ptr[N_NODES] = sh[255];
}

__global__ __launch_bounds__(SCAN_B) void kS3(const int* __restrict__ cnt,
                                              const int* __restrict__ boff,
                                              int* __restrict__ row_ptr,
                                              int* __restrict__ cursor) {
  __shared__ int sh[SCAN_B];
  int t = threadIdx.x;
  int i = blockIdx.x * SCAN_B + t;
  int val = (i < N_NODES) ? cnt[i] : 0;
  sh[t] = val;
  __syncthreads();
  for (int d = 1; d < SCAN_B; d <<= 1) {
    int u = (t >= d) ? sh[t - d] : 0;
    __syncthreads();
    sh[t] += u;
    __syncthreads();
  }
  if (i < N_NODES) {
    int excl = boff[blockIdx.x] + sh[t] - val;
    row_ptr[i] = excl;
    cursor[i] = excl;
  }
}

// ---------------- scatter (NO e_feat read): base = s1[src]+s2[dst]+c
__global__ __launch_bounds__(256) void kE_scatter(
    const int* __restrict__ src, const int* __restrict__ dst,
    const float* __restrict__ s1, const float* __restrict__ s2,
    const float* __restrict__ v, int* __restrict__ cursor,
    unsigned long long* __restrict__ edata) {
  int e = blockIdx.x * 256 + threadIdx.x;
  if (e >= N_EDGES) return;
  int sn = src[e], dn = dst[e];
  float bb = s1[sn] + s2[dn] + v[160];
  int p = atomicAdd(&cursor[dn], 1);
  unsigned long long pk = ((unsigned long long)(unsigned)e << 43) |
                          ((unsigned long long)(unsigned)sn << 26) |
                          (unsigned long long)(__float_as_uint(bb) >> 6);
  edata[p] = pk;
}

// ---------------- K3: one wave per dst node. 8-edge batches; half-wave ef
// gather + in-register dot/exp; bf16 m_src gathers. 12 loads in flight.
__global__ __launch_bounds__(256) void k3_agg(
    const int* __restrict__ row_ptr, const int2* __restrict__ edata,
    const float* __restrict__ e_feat, const unsigned short* __restrict__ m_srcH,
    const unsigned short* __restrict__ m_dstH, const float* __restrict__ v,
    const float* __restrict__ WmeT, const float* __restrict__ Wmsg_b,
    float* __restrict__ out) {
  int lane = threadIdx.x & 63;
  int wid = threadIdx.x >> 6;
  int n = blockIdx.x * 4 + wid;
  if (n >= N_NODES) return;
  int start = row_ptr[n];
  int end = row_ptr[n + 1];
  int half = lane >> 5;  // 0: even edges of batch, 1: odd edges
  int col = lane & 31;
  float v3 = v[128 + col];
  float sum_ex = 0.f, acc_ms = 0.f, acc_ef = 0.f;
  for (int cb = start; cb < end; cb += 64) {
    int2 md = make_int2(0x03FE0000, 0);  // pad: e=0, src=0, base=-inf
    if (cb + lane < end) md = edata[cb + lane];
    int m = end - cb;
    if (m > 64) m = 64;
    int mm8 = (m + 7) & ~7;
    for (int k = 0; k < mm8; k += 8) {
      int ek[8], sk[8];
      float bs[8];
#pragma unroll
      for (int u = 0; u < 8; ++u) {
        unsigned lo = (unsigned)__shfl(md.x, k + u);
        unsigned hi = (unsigned)__shfl(md.y, k + u);
        ek[u] = (int)(hi >> 11);
        sk[u] = (int)(((hi & 0x7FFu) << 6) | (lo >> 26));
        bs[u] = __uint_as_float((lo & 0x3FFFFFFu) << 6);
      }
      // issue all gathers before any consumption
      unsigned short msr[8];
#pragma unroll
      for (int u = 0; u < 8; ++u)
        msr[u] = m_srcH[(size_t)sk[u] * NF + lane];
      float efh[4];
#pragma unroll
      for (int p = 0; p < 4; ++p) {
        int ep = half ? ek[2 * p + 1] : ek[2 * p];
        efh[p] = e_feat[(size_t)ep * EF + col];
      }
      // per-pair logit dot + exp (each half computes its own edge)
      float exq[4];
#pragma unroll
      for (int p = 0; p < 4; ++p) {
        float t = efh[p] * v3;
        t += __shfl_xor(t, 1);
        t += __shfl_xor(t, 2);
        t += __shfl_xor(t, 4);
        t += __shfl_xor(t, 8);
        t += __shfl_xor(t, 16);
        float bb = half ? bs[2 * p + 1] : bs[2 * p];
        float lg = bb + t;
        float l = lg > 0.f ? lg : 0.01f * lg;  // leaky_relu(0.01)
        exq[p] = __expf(l);
        acc_ef = fmaf(exq[p], efh[p], acc_ef);
      }
#pragma unroll
      for (int p = 0; p < 4; ++p) {
        float ex0 = __shfl(exq[p], 0);   // even edge (half0)
        float ex1 = __shfl(exq[p], 32);  // odd edge (half1)
        sum_ex += ex0 + ex1;
        float ms0 = __uint_as_float((unsigned)msr[2 * p] << 16);
        float ms1 = __uint_as_float((unsigned)msr[2 * p + 1] << 16);
        acc_ms = fmaf(ex0, ms0, acc_ms);
        acc_ms = fmaf(ex1, ms1, acc_ms);
      }
    }
  }
  // acc_ef[j] split across halves; mm[lane] = sum_j Wme[lane][j]*acc_ef[j]
  float mm = 0.f;
#pragma unroll
  for (int j = 0; j < 32; ++j) {
    float efj = __shfl(acc_ef, j) + __shfl(acc_ef, j + 32);
    mm = fmaf(WmeT[j * 64 + lane], efj, mm);
  }
  float o = 0.f;
  if (sum_ex > 0.f) {
    float mdv =
        __uint_as_float((unsigned)m_dstH[(size_t)n * NF + lane] << 16);
    o = (acc_ms + mm) / sum_ex + mdv + Wmsg_b[lane];
    o = fmaxf(o, 0.f);
  }
  out[(size_t)n * NF + lane] = o;
}

extern "C" void kernel_launch(void* const* d_in, const int* in_sizes, int n_in,
                              void* d_out, int out_size, void* d_ws,
                              size_t ws_size, hipStream_t stream) {
  const float* n_feat = (const float*)d_in[0];
  const float* e_feat = (const float*)d_in[1];
  const int* src = (const int*)d_in[2];
  const int* dst = (const int*)d_in[3];
  const float* Wmsg_w = (const float*)d_in[4];
  const float* Wmsg_b = (const float*)d_in[5];
  const float* W_w = (const float*)d_in[6];
  const float* W_b = (const float*)d_in[7];
  const float* a = (const float*)d_in[8];
  float* out = (float*)d_out;

  char* ws = (char*)d_ws;
  size_t off = 0;
  auto alloc = [&](size_t bytes) -> char* {
    char* p = ws + off;
    off = (off + bytes + 255) & ~(size_t)255;
    return p;
  };
  float* v = (float*)alloc(161 * 4);
  float* W1T = (float*)alloc(64 * 64 * 4);
  float* W2T = (float*)alloc(64 * 64 * 4);
  float* WmeT = (float*)alloc(32 * 64 * 4);
  float* s1 = (float*)alloc(N_NODES * 4);
  float* s2 = (float*)alloc(N_NODES * 4);
  unsigned* m_srcH = (unsigned*)alloc((size_t)N_NODES * NF * 2);
  unsigned* m_dstH = (unsigned*)alloc((size_t)N_NODES * NF * 2);
  int* cnt = (int*)alloc(N_NODES * 4);
  int* row_ptr = (int*)alloc((N_NODES + 1) * 4);
  int* cursor = (int*)alloc(N_NODES * 4);
  int* bsum = (int*)alloc(SCAN_NB * 4);
  int* boff = (int*)alloc(SCAN_NB * 4);
  unsigned long long* edata = (unsigned long long*)alloc((size_t)N_EDGES * 8);
  if (off > ws_size) return;  // workspace too small — fail loudly in check

  k0_prep<<<1, 256, 0, stream>>>(W_w, W_b, a, Wmsg_w, v, W1T, W2T, WmeT);
  k1_node<<<(N_NODES + 255) / 256, 256, 0, stream>>>(n_feat, v, W1T, W2T, s1,
                                                     s2, m_srcH, m_dstH);
  hipMemsetAsync(cnt, 0, N_NODES * 4, stream);
  k_count<<<(N_EDGES / 4 + 255) / 256, 256, 0, stream>>>((const int4*)dst,
                                                         cnt);
  kS1<<<SCAN_NB, SCAN_B, 0, stream>>>(cnt, bsum);
  kS2<<<1, 256, 0, stream>>>(bsum, boff, row_ptr);
  kS3<<<SCAN_NB, SCAN_B, 0, stream>>>(cnt, boff, row_ptr, cursor);
  kE_scatter<<<(N_EDGES + 255) / 256, 256, 0, stream>>>(src, dst, s1, s2, v,
                                                        cursor, edata);
  k3_agg<<<(N_NODES + 3) / 4, 256, 0, stream>>>(
      row_ptr, (const int2*)edata, e_feat, (const unsigned short*)m_srcH,
      (const unsigned short*)m_dstH, v, WmeT, Wmsg_b, out);
}